// Round 1
// baseline (397.624 us; speedup 1.0000x reference)
//
#include <hip/hip_runtime.h>

// RQ-spline forward: x (65536,512) f32, params (3*512*32) f32 -> y, ld (each 65536*512 f32)
// d_out = [y | ld] concatenated.
//
// Strategy: block owns a 64-dim tile; builds knot tables (x,y,delta,logderiv) in LDS
// once (cumsum of exp over params), then streams 256 rows. Search table xx_s[k][dl]
// banks at dl%32 (2-way, free); gather table knot_s as float4 -> b128 at the 8-phase
// floor. Grid 2048 = 8 dim-tiles x 256 row-groups; 40 KiB LDS -> 4 blocks/CU.

#define NDIMC  512
#define NKNOTC 32
#define NDATAC 65536
#define TILE_D 64
#define NTOT   (NDATAC * NDIMC)

__device__ __forceinline__ float fastrcp(float b) {
    float r = __builtin_amdgcn_rcpf(b);
    return r * (2.0f - b * r);   // one Newton step: ~1-2 ulp
}

__global__ __launch_bounds__(256, 4)
void rqspline_kernel(const float* __restrict__ x_in,
                     const float* __restrict__ params,
                     float* __restrict__ out)
{
    __shared__ float4 knot_s[NKNOTC][TILE_D];  // {xx, yy, delta, logderiv} : 32 KiB
    __shared__ float  xx_s[NKNOTC][TILE_D];    // search copy of xx          : 8 KiB

    const int tid  = threadIdx.x;
    const int tile = blockIdx.x & 7;           // 8 tiles of 64 dims
    const int rgrp = blockIdx.x >> 3;          // 256 row groups of 256 rows
    const int d0   = tile * TILE_D;

    // ---- build per-dim knot tables (threads 0..63, one dim each) ----
    if (tid < TILE_D) {
        const int d = d0 + tid;
        const float x0 = params[d];
        const float y0 = params[NDIMC + d];
        const float* pdx = params + 2 * NDIMC + d * (NKNOTC - 1);
        const float* pdy = params + 2 * NDIMC + NDIMC * (NKNOTC - 1) + d * (NKNOTC - 1);
        const float* pdr = params + 2 * NDIMC + 2 * NDIMC * (NKNOTC - 1) + d * NKNOTC;
        float l0 = pdr[0];
        knot_s[0][tid] = make_float4(x0, y0, expf(l0), l0);
        xx_s[0][tid] = x0;
        float cx = 0.0f, cy = 0.0f;
#pragma unroll 8
        for (int k = 1; k < NKNOTC; ++k) {
            cx += expf(pdx[k - 1]);
            cy += expf(pdy[k - 1]);
            const float xk = x0 + cx;
            const float yk = y0 + cy;
            const float lk = pdr[k];
            knot_s[k][tid] = make_float4(xk, yk, expf(lk), lk);
            xx_s[k][tid] = xk;
        }
    }
    __syncthreads();

    const int wave = tid >> 6;       // 0..3: one row per wave per iter
    const int dl   = tid & 63;       // dim lane within tile
    const int rbase = rgrp * (NDATAC / 256);   // 256 rows per block

#pragma unroll 2
    for (int i = 0; i < 64; ++i) {
        const int r = rbase + i * 4 + wave;
        const int g = r * NDIMC + d0 + dl;
        const float x = __builtin_nontemporal_load(x_in + g);

        // searchsorted-left: c = #{knots < x}, c in [0,32].
        // 5-step uniform binary search over first 31 knots + 1 fix probe.
        int c = 0;
#pragma unroll
        for (int s = 16; s >= 1; s >>= 1) {
            const int p = c + s - 1;
            if (xx_s[p][dl] < x) c = p + 1;
        }
        if (xx_s[c][dl] < x) c += 1;

        const bool sel0 = (c == 0);
        const bool selN = (c == NKNOTC);
        const int ic = min(max(c, 1), NKNOTC - 1);

        const float4 lo = knot_s[ic - 1][dl];
        const float4 hi = knot_s[ic][dl];

        const float invw = fastrcp(hi.x - lo.x);
        const float xc   = fminf(fmaxf(x, lo.x), hi.x);
        const float xi   = (xc - lo.x) * invw;
        const float dy   = hi.y - lo.y;
        const float s_   = dy * invw;
        const float om   = 1.0f - xi;
        const float xi2  = xi * xi;
        const float xi1  = xi * om;
        const float den  = s_ + (hi.z + lo.z - 2.0f * s_) * xi1;
        const float rden = fastrcp(den);

        float y  = lo.y + dy * (s_ * xi2 + lo.z * xi1) * rden;
        // ld_mid = 2 log s + log(num) - 2 log(den) == log(s^2 * num / den^2)
        const float num = hi.z * xi2 + 2.0f * s_ * xi1 + lo.z * om * om;
        float ld = __logf(s_ * s_ * num * (rden * rden));

        if (sel0) { y = lo.y + (x - lo.x) * lo.z; ld = lo.w; }   // linear tail below knot 0
        if (selN) { y = hi.y + (x - hi.x) * hi.z; ld = hi.w; }   // linear tail above knot 31

        __builtin_nontemporal_store(y,  out + g);
        __builtin_nontemporal_store(ld, out + NTOT + g);
    }
}

extern "C" void kernel_launch(void* const* d_in, const int* in_sizes, int n_in,
                              void* d_out, int out_size, void* d_ws, size_t ws_size,
                              hipStream_t stream) {
    const float* x      = (const float*)d_in[0];
    const float* params = (const float*)d_in[1];
    float* out          = (float*)d_out;
    rqspline_kernel<<<dim3(2048), dim3(256), 0, stream>>>(x, params, out);
}